// Round 3
// baseline (1096.389 us; speedup 1.0000x reference)
//
#include <hip/hip_runtime.h>
#include <hip/hip_bf16.h>
#include <math.h>

typedef __attribute__((ext_vector_type(8))) short short8;
typedef __attribute__((ext_vector_type(4))) float f32x4;
typedef __attribute__((ext_vector_type(4))) unsigned short us4;
typedef unsigned short u16;

#define TM 49
#define NV 10000
#define NWG 64

__device__ __forceinline__ u16 f2bf(float f) {
    union { float f; unsigned u; } v; v.f = f;
    unsigned r = v.u + 0x7fffu + ((v.u >> 16) & 1u);
    return (u16)(r >> 16);
}
__device__ __forceinline__ float bf2f(u16 b) {
    union { unsigned u; float f; } v; v.u = ((unsigned)b) << 16;
    return v.f;
}
__device__ __forceinline__ float sigm(float x) { return 1.0f / (1.0f + expf(-x)); }

// ---------------- sort + metadata + small outputs ----------------
__global__ __launch_bounds__(128) void k_sort(
    const int* __restrict__ caplens, const int* __restrict__ captions,
    const float* __restrict__ bih, const float* __restrict__ bhh,
    int* __restrict__ sidx, int* __restrict__ decl, int* __restrict__ capsS,
    float* __restrict__ bsum, float* __restrict__ out_tail,
    unsigned* __restrict__ bar)
{
    __shared__ int s_cl[128];
    __shared__ int s_si[128];
    int tid = threadIdx.x;
    if (tid == 0) bar[0] = 0u;   // reset grid barrier for the persistent kernel
    int my = caplens[tid];
    s_cl[tid] = my;
    __syncthreads();
    int r = 0;
    for (int j = 0; j < 128; j++) {
        int cj = s_cl[j];
        if (cj > my || (cj == my && j < tid)) r++;
    }
    s_si[r] = tid;   // stable descending argsort
    __syncthreads();
    int src = s_si[tid];
    sidx[tid] = src;
    int dl = s_cl[src] - 1;
    decl[tid] = dl;
    out_tail[6400 + tid] = (float)dl;
    out_tail[6528 + tid] = (float)src;
    for (int t = 0; t < 50; t++) {
        int tok = captions[src * 50 + t];
        capsS[tid * 50 + t] = tok;
        out_tail[tid * 50 + t] = (float)tok;
    }
    for (int k = tid; k < 2048; k += 128) bsum[k] = bih[k] + bhh[k];
}

// ---------------- weight fp32 -> bf16 conversion ----------------
__global__ __launch_bounds__(256) void k_cvt(
    const float* __restrict__ Wih, const float* __restrict__ Whh,
    const float* __restrict__ fcW, const float* __restrict__ ihW,
    const float* __restrict__ icW,
    u16* __restrict__ WihB, u16* __restrict__ WhhB,
    u16* __restrict__ fcWB, u16* __restrict__ WhcB)
{
    int idx = blockIdx.x * 256 + threadIdx.x;  // float4 index, exact grid
    const float* src; u16* dst; int o;
    if (idx < 262144)        { src = Wih; dst = WihB; o = idx; }
    else if (idx < 524288)   { src = Whh; dst = WhhB; o = idx - 262144; }
    else if (idx < 1804288)  { src = fcW; dst = fcWB; o = idx - 524288; }
    else if (idx < 2066432)  { src = ihW; dst = WhcB; o = idx - 1804288; }
    else                     { src = icW; dst = WhcB + 1048576; o = idx - 2066432; }
    f32x4 v = *(const f32x4*)&src[(size_t)o * 4];
    us4 b = { f2bf(v.x), f2bf(v.y), f2bf(v.z), f2bf(v.w) };
    *(us4*)&dst[(size_t)o * 4] = b;
}

// ---------------- gathers: sorted enc -> bf16, embedding -> bf16 ----------------
__global__ __launch_bounds__(256) void k_gather(
    const float* __restrict__ enc, const float* __restrict__ embW,
    const int* __restrict__ sidx, const int* __restrict__ capsS,
    u16* __restrict__ encB, u16* __restrict__ Xemb)
{
    int idx = blockIdx.x * 256 + threadIdx.x;
    if (idx < 65536) {
        int b = idx >> 9, k4 = idx & 511;
        f32x4 v = *(const f32x4*)&enc[(size_t)sidx[b] * 2048 + k4 * 4];
        us4 o = { f2bf(v.x), f2bf(v.y), f2bf(v.z), f2bf(v.w) };
        *(us4*)&encB[(size_t)b * 2048 + k4 * 4] = o;
    } else {
        int j = idx - 65536;              // < 802816
        int row = j >> 7, k4 = j & 127;   // row = t*128 + b
        int t = row >> 7, b = row & 127;
        int tok = capsS[b * 50 + t];
        f32x4 v = *(const f32x4*)&embW[(size_t)tok * 512 + k4 * 4];
        us4 o = { f2bf(v.x), f2bf(v.y), f2bf(v.z), f2bf(v.w) };
        *(us4*)&Xemb[(size_t)row * 512 + k4 * 4] = o;
    }
}

// ---------------- generic 128x128 bf16 MFMA GEMM, C = A * B^T ----------------
template<int MODE>
__global__ __launch_bounds__(256) void gemm128(
    const u16* __restrict__ A, int lda,
    const u16* __restrict__ Bm, int ldb, int Nreal, int K,
    const float* __restrict__ bias, const float* __restrict__ bias2,
    const int* __restrict__ dec,
    float* __restrict__ outF, u16* __restrict__ outH, float* __restrict__ outC)
{
    __shared__ u16 As[128][40];
    __shared__ u16 Bs[128][40];
    const int tid = threadIdx.x;
    const int bm = blockIdx.x, bn = blockIdx.y;
    const int w = tid >> 6, l = tid & 63;
    const int wr = (w >> 1) * 64, wc = (w & 1) * 64;
    const int lr = l & 15, lg = l >> 4;

    f32x4 acc[4][4] = {};

    for (int k0 = 0; k0 < K; k0 += 32) {
        __syncthreads();
        #pragma unroll
        for (int i = 0; i < 2; i++) {
            int L = tid * 8 + i * 2048;
            int r = L >> 5, c = L & 31;
            short8 v = *(const short8*)&A[(size_t)(bm * 128 + r) * lda + k0 + c];
            *(short8*)&As[r][c] = v;
        }
        #pragma unroll
        for (int i = 0; i < 2; i++) {
            int L = tid * 8 + i * 2048;
            int r = L >> 5, c = L & 31;
            int gn = bn * 128 + r;
            short8 v = {};
            if (gn < Nreal) v = *(const short8*)&Bm[(size_t)gn * ldb + k0 + c];
            *(short8*)&Bs[r][c] = v;
        }
        __syncthreads();
        short8 af[4], bfr[4];
        #pragma unroll
        for (int m = 0; m < 4; m++) af[m] = *(const short8*)&As[wr + m * 16 + lr][lg * 8];
        #pragma unroll
        for (int n = 0; n < 4; n++) bfr[n] = *(const short8*)&Bs[wc + n * 16 + lr][lg * 8];
        #pragma unroll
        for (int m = 0; m < 4; m++)
            #pragma unroll
            for (int n = 0; n < 4; n++)
                acc[m][n] = __builtin_amdgcn_mfma_f32_16x16x32_bf16(af[m], bfr[n], acc[m][n], 0, 0, 0);
    }

    #pragma unroll
    for (int m = 0; m < 4; m++) {
        #pragma unroll
        for (int n = 0; n < 4; n++) {
            #pragma unroll
            for (int i = 0; i < 4; i++) {
                int row = bm * 128 + wr + m * 16 + lg * 4 + i;
                int col = bn * 128 + wc + n * 16 + lr;
                float v = acc[m][n][i];
                if (MODE == 0) {
                    outF[(size_t)row * 2048 + col] = v + bias[col];
                } else if (MODE == 1) {
                    if (col < 512) outH[row * 512 + col] = f2bf(v + bias[col]);
                    else outC[row * 512 + (col - 512)] = v + bias2[col - 512];
                } else {
                    if (col < Nreal) {
                        int b = row & 127, t = row >> 7;
                        float o = (t < dec[b]) ? (v + bias[col]) : 0.0f;
                        outF[(size_t)b * ((size_t)TM * NV) + (size_t)t * NV + col] = o;
                    }
                }
            }
        }
    }
}

// ---------------- persistent LSTM: all 49 steps in one kernel ----------------
// 64 WGs = 4 row-blocks x 16 col-blocks; WG owns its 32x32 h/c tile for all steps.
// Whh fragments live in registers (loaded once); c lives in registers.
__global__ __launch_bounds__(256, 1) void lstm_all(
    const u16* __restrict__ Whh, const float* __restrict__ X,
    u16* __restrict__ hb0, u16* __restrict__ hb1,
    const float* __restrict__ cf, u16* __restrict__ Hnew,
    const int* __restrict__ decl, unsigned* __restrict__ bar)
{
    __shared__ u16 As[32][520];       // h rows, full K=512, padded (2-way conflict only)
    __shared__ float gs[4][32][40];   // gate exchange
    const int tid = threadIdx.x;
    const int wg = blockIdx.x;
    const int rb = wg >> 4, cb = wg & 15;
    const int g = tid >> 6, l = tid & 63;
    const int lr = l & 15, lg = l >> 4;

    // epilogue coords (fixed across steps)
    const int erow = tid >> 3;            // 0..31
    const int ec4  = (tid & 7) * 4;       // 0..28
    const int egr  = rb * 32 + erow;      // batch row (sorted)
    const int egc  = cb * 32 + ec4;       // hidden col
    const int edec = decl[egr];

    // c state in registers (exclusive ownership)
    f32x4 creg = *(const f32x4*)&cf[(size_t)egr * 512 + egc];

    // Whh -> registers, once. bq[n][kk] = frag of Whh row (g*512+cb*32+n*16+lr), k = kk*32+lg*8
    short8 bq[2][16];
    #pragma unroll
    for (int n = 0; n < 2; n++) {
        const u16* base = &Whh[(size_t)(g * 512 + cb * 32 + n * 16 + lr) * 512 + lg * 8];
        #pragma unroll
        for (int kk = 0; kk < 16; kk++)
            bq[n][kk] = *(const short8*)&base[kk * 32];
    }

    for (int t = 0; t < TM; t++) {
        const u16* hin = (t & 1) ? hb1 : hb0;
        u16* hout = (t & 1) ? hb0 : hb1;

        // stage 32 rows x 512 cols of h into LDS
        #pragma unroll
        for (int i = 0; i < 8; i++) {
            int L = tid * 8 + i * 2048;
            int r = L >> 9, cc = L & 511;
            *(short8*)&As[r][cc] = *(const short8*)&hin[(size_t)(rb * 32 + r) * 512 + cc];
        }
        __syncthreads();

        f32x4 acc[2][2] = {};
        #pragma unroll
        for (int kk = 0; kk < 16; kk++) {
            short8 af0 = *(const short8*)&As[lr][kk * 32 + lg * 8];
            short8 af1 = *(const short8*)&As[16 + lr][kk * 32 + lg * 8];
            acc[0][0] = __builtin_amdgcn_mfma_f32_16x16x32_bf16(af0, bq[0][kk], acc[0][0], 0, 0, 0);
            acc[0][1] = __builtin_amdgcn_mfma_f32_16x16x32_bf16(af0, bq[1][kk], acc[0][1], 0, 0, 0);
            acc[1][0] = __builtin_amdgcn_mfma_f32_16x16x32_bf16(af1, bq[0][kk], acc[1][0], 0, 0, 0);
            acc[1][1] = __builtin_amdgcn_mfma_f32_16x16x32_bf16(af1, bq[1][kk], acc[1][1], 0, 0, 0);
        }

        #pragma unroll
        for (int m = 0; m < 2; m++)
            #pragma unroll
            for (int n = 0; n < 2; n++)
                #pragma unroll
                for (int i = 0; i < 4; i++)
                    gs[g][m * 16 + lg * 4 + i][n * 16 + lr] = acc[m][n][i];
        __syncthreads();

        {
            f32x4 gi = *(const f32x4*)&gs[0][erow][ec4];
            f32x4 gf = *(const f32x4*)&gs[1][erow][ec4];
            f32x4 gg = *(const f32x4*)&gs[2][erow][ec4];
            f32x4 go = *(const f32x4*)&gs[3][erow][ec4];
            const float* Xt = X + (size_t)t * 262144;
            size_t xb = (size_t)egr * 2048 + egc;
            f32x4 xi = *(const f32x4*)&Xt[xb];
            f32x4 xf = *(const f32x4*)&Xt[xb + 512];
            f32x4 xg = *(const f32x4*)&Xt[xb + 1024];
            f32x4 xo = *(const f32x4*)&Xt[xb + 1536];
            int act = (t < edec);
            us4 hv, hn;
            #pragma unroll
            for (int j = 0; j < 4; j++) {
                float iv = sigm(gi[j] + xi[j]);
                float fv = sigm(gf[j] + xf[j]);
                float gv = tanhf(gg[j] + xg[j]);
                float ov = sigm(go[j] + xo[j]);
                float cn = fv * creg[j] + iv * gv;
                float hn_f = ov * tanhf(cn);
                creg[j] = act ? cn : creg[j];
                float hold = bf2f(As[erow][egc + j]);
                float ho = act ? hn_f : hold;
                hv[j] = f2bf(ho);
                hn[j] = f2bf(hn_f);
            }
            *(us4*)&hout[(size_t)egr * 512 + egc] = hv;
            *(us4*)&Hnew[(size_t)t * 65536 + (size_t)egr * 512 + egc] = hn;
        }

        // grid-wide barrier (device-scope fences for cross-XCD visibility of hout)
        if (t < TM - 1) {
            __threadfence();
            __syncthreads();
            if (tid == 0) {
                atomicAdd(bar, 1u);
                unsigned target = (unsigned)NWG * (unsigned)(t + 1);
                while (atomicAdd(bar, 0u) < target) __builtin_amdgcn_s_sleep(1);
            }
            __syncthreads();
            __threadfence();
        }
    }
}

extern "C" void kernel_launch(void* const* d_in, const int* in_sizes, int n_in,
                              void* d_out, int out_size, void* d_ws, size_t ws_size,
                              hipStream_t stream) {
    const float* enc      = (const float*)d_in[0];
    const int*   captions = (const int*)d_in[1];
    const int*   caplens  = (const int*)d_in[2];
    const float* embW     = (const float*)d_in[3];
    const float* Wih      = (const float*)d_in[4];
    const float* Whh      = (const float*)d_in[5];
    const float* bih      = (const float*)d_in[6];
    const float* bhh      = (const float*)d_in[7];
    const float* fcW      = (const float*)d_in[8];
    const float* fcb      = (const float*)d_in[9];
    const float* ihW      = (const float*)d_in[10];
    const float* ihb      = (const float*)d_in[11];
    const float* icW      = (const float*)d_in[12];
    const float* icb      = (const float*)d_in[13];
    float* out = (float*)d_out;

    char* ws = (char*)d_ws;
    u16*   WihB = (u16*)(ws + 0);
    u16*   WhhB = (u16*)(ws + 2097152);
    u16*   fcWB = (u16*)(ws + 4194304);
    u16*   WhcB = (u16*)(ws + 14434304);
    u16*   encB = (u16*)(ws + 18628608);
    u16*   Xemb = (u16*)(ws + 19152896);
    float* X    = (float*)(ws + 25575424);
    u16*   Hnew = (u16*)(ws + 76955648);
    u16*   hb0  = (u16*)(ws + 83378176);
    u16*   hb1  = (u16*)(ws + 83509248);
    float* cf   = (float*)(ws + 83640320);
    int*   sidx = (int*)(ws + 83902464);
    int*   decl = (int*)(ws + 83902976);
    int*   capsS= (int*)(ws + 83903488);
    float* bsum = (float*)(ws + 83929088);
    unsigned* bar = (unsigned*)(ws + 83937280);

    k_sort<<<1, 128, 0, stream>>>(caplens, captions, bih, bhh, sidx, decl, capsS, bsum,
                                  out + 62720000, bar);
    k_cvt<<<9096, 256, 0, stream>>>(Wih, Whh, fcW, ihW, icW, WihB, WhhB, fcWB, WhcB);
    k_gather<<<3392, 256, 0, stream>>>(enc, embW, sidx, capsS, encB, Xemb);
    // h0 | c0 : (128 x 1024) = encB (128x2048) @ WhcB^T
    gemm128<1><<<dim3(1, 8), 256, 0, stream>>>(encB, 2048, WhcB, 2048, 1024, 2048,
                                               ihb, icb, nullptr, nullptr, hb0, cf);
    // X = Xemb (6272x512) @ WihB^T (2048x512) + (b_ih+b_hh)
    gemm128<0><<<dim3(49, 16), 256, 0, stream>>>(Xemb, 512, WihB, 512, 2048, 512,
                                                 bsum, nullptr, nullptr, X, nullptr, nullptr);
    // all 49 LSTM steps in one persistent kernel
    lstm_all<<<NWG, 256, 0, stream>>>(WhhB, X, hb0, hb1, cf, Hnew, decl, bar);
    // predictions = Hnew (6272x512) @ fcWB^T (10000x512) + fc_b, masked
    gemm128<2><<<dim3(49, 79), 256, 0, stream>>>(Hnew, 512, fcWB, 512, NV, 512,
                                                 fcb, nullptr, decl, out, nullptr, nullptr);
}

// Round 5
// 762.181 us; speedup vs baseline: 1.4385x; 1.4385x over previous
//
#include <hip/hip_runtime.h>
#include <hip/hip_bf16.h>
#include <math.h>

typedef __attribute__((ext_vector_type(8))) short short8;
typedef __attribute__((ext_vector_type(4))) float f32x4;
typedef __attribute__((ext_vector_type(4))) unsigned short us4;
typedef unsigned short u16;
typedef unsigned long long u64;

#define TM 49
#define NV 10000
#define NWG 64

union U64c { us4 v; u64 u; };

__device__ __forceinline__ u16 f2bf(float f) {
    union { float f; unsigned u; } v; v.f = f;
    unsigned r = v.u + 0x7fffu + ((v.u >> 16) & 1u);
    return (u16)(r >> 16);
}
__device__ __forceinline__ float bf2f(u16 b) {
    union { unsigned u; float f; } v; v.u = ((unsigned)b) << 16;
    return v.f;
}
__device__ __forceinline__ float sigm(float x) { return 1.0f / (1.0f + expf(-x)); }

// ---------------- sort + metadata + small outputs ----------------
__global__ __launch_bounds__(128) void k_sort(
    const int* __restrict__ caplens, const int* __restrict__ captions,
    const float* __restrict__ bih, const float* __restrict__ bhh,
    int* __restrict__ sidx, int* __restrict__ decl, int* __restrict__ capsS,
    float* __restrict__ bsum, float* __restrict__ out_tail,
    unsigned* __restrict__ slots)
{
    __shared__ int s_cl[128];
    __shared__ int s_si[128];
    int tid = threadIdx.x;
    if (tid < NWG)   // reset barrier slots for the persistent kernel
        __hip_atomic_store(&slots[tid], 0u, __ATOMIC_RELAXED, __HIP_MEMORY_SCOPE_AGENT);
    int my = caplens[tid];
    s_cl[tid] = my;
    __syncthreads();
    int r = 0;
    for (int j = 0; j < 128; j++) {
        int cj = s_cl[j];
        if (cj > my || (cj == my && j < tid)) r++;
    }
    s_si[r] = tid;   // stable descending argsort
    __syncthreads();
    int src = s_si[tid];
    sidx[tid] = src;
    int dl = s_cl[src] - 1;
    decl[tid] = dl;
    out_tail[6400 + tid] = (float)dl;
    out_tail[6528 + tid] = (float)src;
    for (int t = 0; t < 50; t++) {
        int tok = captions[src * 50 + t];
        capsS[tid * 50 + t] = tok;
        out_tail[tid * 50 + t] = (float)tok;
    }
    for (int k = tid; k < 2048; k += 128) bsum[k] = bih[k] + bhh[k];
}

// ---------------- weight fp32 -> bf16 conversion ----------------
__global__ __launch_bounds__(256) void k_cvt(
    const float* __restrict__ Wih, const float* __restrict__ Whh,
    const float* __restrict__ fcW, const float* __restrict__ ihW,
    const float* __restrict__ icW,
    u16* __restrict__ WihB, u16* __restrict__ WhhB,
    u16* __restrict__ fcWB, u16* __restrict__ WhcB)
{
    int idx = blockIdx.x * 256 + threadIdx.x;  // float4 index, exact grid
    const float* src; u16* dst; int o;
    if (idx < 262144)        { src = Wih; dst = WihB; o = idx; }
    else if (idx < 524288)   { src = Whh; dst = WhhB; o = idx - 262144; }
    else if (idx < 1804288)  { src = fcW; dst = fcWB; o = idx - 524288; }
    else if (idx < 2066432)  { src = ihW; dst = WhcB; o = idx - 1804288; }
    else                     { src = icW; dst = WhcB + 1048576; o = idx - 2066432; }
    f32x4 v = *(const f32x4*)&src[(size_t)o * 4];
    us4 b = { f2bf(v.x), f2bf(v.y), f2bf(v.z), f2bf(v.w) };
    *(us4*)&dst[(size_t)o * 4] = b;
}

// ---------------- gathers: sorted enc -> bf16, embedding -> bf16 ----------------
__global__ __launch_bounds__(256) void k_gather(
    const float* __restrict__ enc, const float* __restrict__ embW,
    const int* __restrict__ sidx, const int* __restrict__ capsS,
    u16* __restrict__ encB, u16* __restrict__ Xemb)
{
    int idx = blockIdx.x * 256 + threadIdx.x;
    if (idx < 65536) {
        int b = idx >> 9, k4 = idx & 511;
        f32x4 v = *(const f32x4*)&enc[(size_t)sidx[b] * 2048 + k4 * 4];
        us4 o = { f2bf(v.x), f2bf(v.y), f2bf(v.z), f2bf(v.w) };
        *(us4*)&encB[(size_t)b * 2048 + k4 * 4] = o;
    } else {
        int j = idx - 65536;              // < 802816
        int row = j >> 7, k4 = j & 127;   // row = t*128 + b
        int t = row >> 7, b = row & 127;
        int tok = capsS[b * 50 + t];
        f32x4 v = *(const f32x4*)&embW[(size_t)tok * 512 + k4 * 4];
        us4 o = { f2bf(v.x), f2bf(v.y), f2bf(v.z), f2bf(v.w) };
        *(us4*)&Xemb[(size_t)row * 512 + k4 * 4] = o;
    }
}

// ---------------- generic 128x128 bf16 MFMA GEMM, C = A * B^T ----------------
// 1D grid with grouped-supertile ordering for XCD/L2 locality.
template<int MODE>
__global__ __launch_bounds__(256) void gemm128(
    const u16* __restrict__ A, int lda,
    const u16* __restrict__ Bm, int ldb, int Nreal, int K,
    int GM, int GN,
    const float* __restrict__ bias, const float* __restrict__ bias2,
    const int* __restrict__ dec,
    float* __restrict__ outF, u16* __restrict__ outH, float* __restrict__ outC)
{
    __shared__ u16 As[128][40];
    __shared__ u16 Bs[128][40];
    const int tid = threadIdx.x;
    const int GROUP = 8;
    int pid = blockIdx.x;
    int bpg = GROUP * GN;
    int group = pid / bpg;
    int first = group * GROUP;
    int gsz = min(GM - first, GROUP);
    int rem = pid - group * bpg;
    int bm = first + rem % gsz;
    int bn = rem / gsz;

    const int w = tid >> 6, l = tid & 63;
    const int wr = (w >> 1) * 64, wc = (w & 1) * 64;
    const int lr = l & 15, lg = l >> 4;

    f32x4 acc[4][4] = {};

    for (int k0 = 0; k0 < K; k0 += 32) {
        __syncthreads();
        #pragma unroll
        for (int i = 0; i < 2; i++) {
            int L = tid * 8 + i * 2048;
            int r = L >> 5, c = L & 31;
            short8 v = *(const short8*)&A[(size_t)(bm * 128 + r) * lda + k0 + c];
            *(short8*)&As[r][c] = v;
        }
        #pragma unroll
        for (int i = 0; i < 2; i++) {
            int L = tid * 8 + i * 2048;
            int r = L >> 5, c = L & 31;
            int gn = bn * 128 + r;
            short8 v = {};
            if (gn < Nreal) v = *(const short8*)&Bm[(size_t)gn * ldb + k0 + c];
            *(short8*)&Bs[r][c] = v;
        }
        __syncthreads();
        short8 af[4], bfr[4];
        #pragma unroll
        for (int m = 0; m < 4; m++) af[m] = *(const short8*)&As[wr + m * 16 + lr][lg * 8];
        #pragma unroll
        for (int n = 0; n < 4; n++) bfr[n] = *(const short8*)&Bs[wc + n * 16 + lr][lg * 8];
        #pragma unroll
        for (int m = 0; m < 4; m++)
            #pragma unroll
            for (int n = 0; n < 4; n++)
                acc[m][n] = __builtin_amdgcn_mfma_f32_16x16x32_bf16(af[m], bfr[n], acc[m][n], 0, 0, 0);
    }

    #pragma unroll
    for (int m = 0; m < 4; m++) {
        #pragma unroll
        for (int n = 0; n < 4; n++) {
            #pragma unroll
            for (int i = 0; i < 4; i++) {
                int row = bm * 128 + wr + m * 16 + lg * 4 + i;
                int col = bn * 128 + wc + n * 16 + lr;
                float v = acc[m][n][i];
                if (MODE == 0) {
                    outF[(size_t)row * 2048 + col] = v + bias[col];
                } else if (MODE == 1) {
                    if (col < 512) outH[row * 512 + col] = f2bf(v + bias[col]);
                    else outC[row * 512 + (col - 512)] = v + bias2[col - 512];
                } else {
                    if (col < Nreal) {
                        int b = row & 127, t = row >> 7;
                        float o = (t < dec[b]) ? (v + bias[col]) : 0.0f;
                        outF[(size_t)b * ((size_t)TM * NV) + (size_t)t * NV + col] = o;
                    }
                }
            }
        }
    }
}

// ---------------- persistent LSTM: all 49 steps in one kernel ----------------
// h state exchanged via agent-scope relaxed atomics (device coherence point,
// no fences). Grid barrier: per-WG epoch slot store + wave0 polling loads.
__global__ __launch_bounds__(256, 1) void lstm_all(
    const u16* __restrict__ Whh, const float* __restrict__ X,
    u16* __restrict__ hb0, u16* __restrict__ hb1,
    const float* __restrict__ cf, u16* __restrict__ Hnew,
    const int* __restrict__ decl, unsigned* __restrict__ slots)
{
    __shared__ u16 As[32][520];       // h rows, full K=512, padded
    __shared__ float gs[4][32][40];   // gate exchange
    const int tid = threadIdx.x;
    const int wg = blockIdx.x;
    const int rb = wg >> 4, cb = wg & 15;
    const int g = tid >> 6, l = tid & 63;
    const int lr = l & 15, lg = l >> 4;

    // epilogue coords (fixed across steps)
    const int erow = tid >> 3;            // 0..31
    const int ec4  = (tid & 7) * 4;       // 0..28
    const int egr  = rb * 32 + erow;      // batch row (sorted)
    const int egc  = cb * 32 + ec4;       // hidden col
    const int edec = decl[egr];

    // c state in registers (exclusive ownership)
    f32x4 creg = *(const f32x4*)&cf[(size_t)egr * 512 + egc];

    // Whh -> registers, once
    short8 bq[2][16];
    #pragma unroll
    for (int n = 0; n < 2; n++) {
        const u16* base = &Whh[(size_t)(g * 512 + cb * 32 + n * 16 + lr) * 512 + lg * 8];
        #pragma unroll
        for (int kk = 0; kk < 16; kk++)
            bq[n][kk] = *(const short8*)&base[kk * 32];
    }

    for (int t = 0; t < TM; t++) {
        const u16* hin = (t & 1) ? hb1 : hb0;
        u16* hout = (t & 1) ? hb0 : hb1;

        // stage 32 rows x 512 cols of h into LDS via coherence-point atomic loads.
        // u64 index: each 512-u16 row = 128 u64  ->  r = L>>7, col4 = (L&127)*4
        #pragma unroll
        for (int i = 0; i < 16; i++) {
            int L = i * 256 + tid;          // u64 index; 4096 total
            int r = L >> 7, cc = (L & 127) * 4;
            U64c u;
            u.u = __hip_atomic_load((const u64*)&hin[(size_t)(rb * 32 + r) * 512 + cc],
                                    __ATOMIC_RELAXED, __HIP_MEMORY_SCOPE_AGENT);
            *(us4*)&As[r][cc] = u.v;
        }
        __syncthreads();

        f32x4 acc[2][2] = {};
        #pragma unroll
        for (int kk = 0; kk < 16; kk++) {
            short8 af0 = *(const short8*)&As[lr][kk * 32 + lg * 8];
            short8 af1 = *(const short8*)&As[16 + lr][kk * 32 + lg * 8];
            acc[0][0] = __builtin_amdgcn_mfma_f32_16x16x32_bf16(af0, bq[0][kk], acc[0][0], 0, 0, 0);
            acc[0][1] = __builtin_amdgcn_mfma_f32_16x16x32_bf16(af0, bq[1][kk], acc[0][1], 0, 0, 0);
            acc[1][0] = __builtin_amdgcn_mfma_f32_16x16x32_bf16(af1, bq[0][kk], acc[1][0], 0, 0, 0);
            acc[1][1] = __builtin_amdgcn_mfma_f32_16x16x32_bf16(af1, bq[1][kk], acc[1][1], 0, 0, 0);
        }

        #pragma unroll
        for (int m = 0; m < 2; m++)
            #pragma unroll
            for (int n = 0; n < 2; n++)
                #pragma unroll
                for (int i = 0; i < 4; i++)
                    gs[g][m * 16 + lg * 4 + i][n * 16 + lr] = acc[m][n][i];
        __syncthreads();

        {
            f32x4 gi = *(const f32x4*)&gs[0][erow][ec4];
            f32x4 gf = *(const f32x4*)&gs[1][erow][ec4];
            f32x4 gg = *(const f32x4*)&gs[2][erow][ec4];
            f32x4 go = *(const f32x4*)&gs[3][erow][ec4];
            const float* Xt = X + (size_t)t * 262144;
            size_t xb = (size_t)egr * 2048 + egc;
            f32x4 xi = *(const f32x4*)&Xt[xb];
            f32x4 xf = *(const f32x4*)&Xt[xb + 512];
            f32x4 xg = *(const f32x4*)&Xt[xb + 1024];
            f32x4 xo = *(const f32x4*)&Xt[xb + 1536];
            int act = (t < edec);
            us4 hv, hn;
            #pragma unroll
            for (int j = 0; j < 4; j++) {
                float iv = sigm(gi[j] + xi[j]);
                float fv = sigm(gf[j] + xf[j]);
                float gv = tanhf(gg[j] + xg[j]);
                float ov = sigm(go[j] + xo[j]);
                float cn = fv * creg[j] + iv * gv;
                float hn_f = ov * tanhf(cn);
                creg[j] = act ? cn : creg[j];
                float hold = bf2f(As[erow][egc + j]);
                float ho = act ? hn_f : hold;
                hv[j] = f2bf(ho);
                hn[j] = f2bf(hn_f);
            }
            U64c hu; hu.v = hv;
            __hip_atomic_store((u64*)&hout[(size_t)egr * 512 + egc], hu.u,
                               __ATOMIC_RELAXED, __HIP_MEMORY_SCOPE_AGENT);
            *(us4*)&Hnew[(size_t)t * 65536 + (size_t)egr * 512 + egc] = hn;
        }

        // grid barrier: syncthreads drains vmcnt (stores visible), slot store, poll
        if (t < TM - 1) {
            __syncthreads();
            if (tid == 0)
                __hip_atomic_store(&slots[wg], (unsigned)(t + 1),
                                   __ATOMIC_RELAXED, __HIP_MEMORY_SCOPE_AGENT);
            if (tid < NWG) {
                while (__hip_atomic_load(&slots[tid], __ATOMIC_RELAXED,
                                         __HIP_MEMORY_SCOPE_AGENT) <= (unsigned)t)
                    __builtin_amdgcn_s_sleep(2);
            }
            __syncthreads();
        }
    }
}

extern "C" void kernel_launch(void* const* d_in, const int* in_sizes, int n_in,
                              void* d_out, int out_size, void* d_ws, size_t ws_size,
                              hipStream_t stream) {
    const float* enc      = (const float*)d_in[0];
    const int*   captions = (const int*)d_in[1];
    const int*   caplens  = (const int*)d_in[2];
    const float* embW     = (const float*)d_in[3];
    const float* Wih      = (const float*)d_in[4];
    const float* Whh      = (const float*)d_in[5];
    const float* bih      = (const float*)d_in[6];
    const float* bhh      = (const float*)d_in[7];
    const float* fcW      = (const float*)d_in[8];
    const float* fcb      = (const float*)d_in[9];
    const float* ihW      = (const float*)d_in[10];
    const float* ihb      = (const float*)d_in[11];
    const float* icW      = (const float*)d_in[12];
    const float* icb      = (const float*)d_in[13];
    float* out = (float*)d_out;

    char* ws = (char*)d_ws;
    u16*   WihB = (u16*)(ws + 0);
    u16*   WhhB = (u16*)(ws + 2097152);
    u16*   fcWB = (u16*)(ws + 4194304);
    u16*   WhcB = (u16*)(ws + 14434304);
    u16*   encB = (u16*)(ws + 18628608);
    u16*   Xemb = (u16*)(ws + 19152896);
    float* X    = (float*)(ws + 25575424);
    u16*   Hnew = (u16*)(ws + 76955648);
    u16*   hb0  = (u16*)(ws + 83378176);
    u16*   hb1  = (u16*)(ws + 83509248);
    float* cf   = (float*)(ws + 83640320);
    int*   sidx = (int*)(ws + 83902464);
    int*   decl = (int*)(ws + 83902976);
    int*   capsS= (int*)(ws + 83903488);
    float* bsum = (float*)(ws + 83929088);
    unsigned* slots = (unsigned*)(ws + 83937280);

    k_sort<<<1, 128, 0, stream>>>(caplens, captions, bih, bhh, sidx, decl, capsS, bsum,
                                  out + 62720000, slots);
    k_cvt<<<9096, 256, 0, stream>>>(Wih, Whh, fcW, ihW, icW, WihB, WhhB, fcWB, WhcB);
    k_gather<<<3392, 256, 0, stream>>>(enc, embW, sidx, capsS, encB, Xemb);
    // h0 | c0 : (128 x 1024) = encB (128x2048) @ WhcB^T
    gemm128<1><<<8, 256, 0, stream>>>(encB, 2048, WhcB, 2048, 1024, 2048, 1, 8,
                                      ihb, icb, nullptr, nullptr, hb0, cf);
    // X = Xemb (6272x512) @ WihB^T (2048x512) + (b_ih+b_hh)
    gemm128<0><<<784, 256, 0, stream>>>(Xemb, 512, WihB, 512, 2048, 512, 49, 16,
                                        bsum, nullptr, nullptr, X, nullptr, nullptr);
    // all 49 LSTM steps in one persistent kernel
    lstm_all<<<NWG, 256, 0, stream>>>(WhhB, X, hb0, hb1, cf, Hnew, decl, slots);
    // predictions = Hnew (6272x512) @ fcWB^T (10000x512) + fc_b, masked
    gemm128<2><<<3871, 256, 0, stream>>>(Hnew, 512, fcWB, 512, NV, 512, 49, 79,
                                         fcb, nullptr, decl, out, nullptr, nullptr);
}

// Round 6
// 648.344 us; speedup vs baseline: 1.6911x; 1.1756x over previous
//
#include <hip/hip_runtime.h>
#include <hip/hip_bf16.h>
#include <math.h>

typedef __attribute__((ext_vector_type(8))) short short8;
typedef __attribute__((ext_vector_type(4))) float f32x4;
typedef __attribute__((ext_vector_type(4))) unsigned short us4;
typedef unsigned short u16;
typedef unsigned long long u64;

#define TM 49
#define NV 10000
#define NWG 64

union U64c { us4 v; u64 u; };

__device__ __forceinline__ u16 f2bf(float f) {
    union { float f; unsigned u; } v; v.f = f;
    unsigned r = v.u + 0x7fffu + ((v.u >> 16) & 1u);
    return (u16)(r >> 16);
}
__device__ __forceinline__ float bf2f(u16 b) {
    union { unsigned u; float f; } v; v.u = ((unsigned)b) << 16;
    return v.f;
}
__device__ __forceinline__ float sigm(float x) { return 1.0f / (1.0f + expf(-x)); }

// ---------------- sort + metadata + compaction tables + small outputs ----------------
__global__ __launch_bounds__(128) void k_sort(
    const int* __restrict__ caplens, const int* __restrict__ captions,
    const float* __restrict__ bih, const float* __restrict__ bhh,
    int* __restrict__ sidx, int* __restrict__ decl, int* __restrict__ capsS,
    float* __restrict__ bsum, float* __restrict__ out_tail,
    unsigned* __restrict__ slots, int* __restrict__ offs, int* __restrict__ rowmap)
{
    __shared__ int s_cl[128];
    __shared__ int s_si[128];
    __shared__ int s_dl[128];
    __shared__ int s_n[49];
    __shared__ int s_off[50];
    int tid = threadIdx.x;
    for (int k = tid; k < 256; k += 128)   // reset per-group barrier slots
        __hip_atomic_store(&slots[k], 0u, __ATOMIC_RELAXED, __HIP_MEMORY_SCOPE_AGENT);
    int my = caplens[tid];
    s_cl[tid] = my;
    __syncthreads();
    int r = 0;
    for (int j = 0; j < 128; j++) {
        int cj = s_cl[j];
        if (cj > my || (cj == my && j < tid)) r++;
    }
    s_si[r] = tid;   // stable descending argsort
    __syncthreads();
    int src = s_si[tid];
    sidx[tid] = src;
    int dl = s_cl[src] - 1;
    decl[tid] = dl;
    s_dl[tid] = dl;
    out_tail[6400 + tid] = (float)dl;
    out_tail[6528 + tid] = (float)src;
    for (int t = 0; t < 50; t++) {
        int tok = captions[src * 50 + t];
        capsS[tid * 50 + t] = tok;
        out_tail[tid * 50 + t] = (float)tok;
    }
    for (int k = tid; k < 2048; k += 128) bsum[k] = bih[k] + bhh[k];
    __syncthreads();
    // n_t = #valid rows at step t (rows sorted desc -> valid rows are prefix 0..n_t)
    if (tid < 49) {
        int c = 0;
        for (int b = 0; b < 128; b++) c += (s_dl[b] > tid);
        s_n[tid] = c;
    }
    __syncthreads();
    if (tid == 0) {
        int a = 0;
        for (int t = 0; t < 49; t++) { s_off[t] = a; a += s_n[t]; }
        s_off[49] = a;   // total compacted rows
    }
    __syncthreads();
    if (tid < 50) offs[tid] = s_off[tid];
    for (int t = 0; t < dl; t++) rowmap[s_off[t] + tid] = t * 128 + tid;
}

// ---------------- zero-fill masked prediction rows ----------------
__global__ __launch_bounds__(256) void k_zero(
    const int* __restrict__ decl, float* __restrict__ out)
{
    int r = blockIdx.x;           // 0..6271
    int b = r / 49, t = r - b * 49;
    if (t < decl[b]) return;
    float* dst = out + (size_t)b * 490000 + (size_t)t * 10000;
    f32x4 z = {};
    for (int i = threadIdx.x; i < 2500; i += 256) *(f32x4*)&dst[i * 4] = z;
}

// ---------------- weight fp32 -> bf16 conversion ----------------
__global__ __launch_bounds__(256) void k_cvt(
    const float* __restrict__ Wih, const float* __restrict__ Whh,
    const float* __restrict__ fcW, const float* __restrict__ ihW,
    const float* __restrict__ icW,
    u16* __restrict__ WihB, u16* __restrict__ WhhB,
    u16* __restrict__ fcWB, u16* __restrict__ WhcB)
{
    int idx = blockIdx.x * 256 + threadIdx.x;  // float4 index, exact grid
    const float* src; u16* dst; int o;
    if (idx < 262144)        { src = Wih; dst = WihB; o = idx; }
    else if (idx < 524288)   { src = Whh; dst = WhhB; o = idx - 262144; }
    else if (idx < 1804288)  { src = fcW; dst = fcWB; o = idx - 524288; }
    else if (idx < 2066432)  { src = ihW; dst = WhcB; o = idx - 1804288; }
    else                     { src = icW; dst = WhcB + 1048576; o = idx - 2066432; }
    f32x4 v = *(const f32x4*)&src[(size_t)o * 4];
    us4 b = { f2bf(v.x), f2bf(v.y), f2bf(v.z), f2bf(v.w) };
    *(us4*)&dst[(size_t)o * 4] = b;
}

// ---------------- gathers: sorted enc -> bf16, embedding -> bf16 ----------------
__global__ __launch_bounds__(256) void k_gather(
    const float* __restrict__ enc, const float* __restrict__ embW,
    const int* __restrict__ sidx, const int* __restrict__ capsS,
    u16* __restrict__ encB, u16* __restrict__ Xemb)
{
    int idx = blockIdx.x * 256 + threadIdx.x;
    if (idx < 65536) {
        int b = idx >> 9, k4 = idx & 511;
        f32x4 v = *(const f32x4*)&enc[(size_t)sidx[b] * 2048 + k4 * 4];
        us4 o = { f2bf(v.x), f2bf(v.y), f2bf(v.z), f2bf(v.w) };
        *(us4*)&encB[(size_t)b * 2048 + k4 * 4] = o;
    } else {
        int j = idx - 65536;              // < 802816
        int row = j >> 7, k4 = j & 127;   // row = t*128 + b
        int t = row >> 7, b = row & 127;
        int tok = capsS[b * 50 + t];
        f32x4 v = *(const f32x4*)&embW[(size_t)tok * 512 + k4 * 4];
        us4 o = { f2bf(v.x), f2bf(v.y), f2bf(v.z), f2bf(v.w) };
        *(us4*)&Xemb[(size_t)row * 512 + k4 * 4] = o;
    }
}

// ---------------- generic 128x128 bf16 MFMA GEMM, C = A * B^T ----------------
// 1D grid with grouped-supertile ordering for XCD/L2 locality.
// MODE 0: X-precompute. MODE 1: h0/c0. MODE 2: fc on COMPACTED rows (rowmap scatter).
template<int MODE>
__global__ __launch_bounds__(256) void gemm128(
    const u16* __restrict__ A, int lda,
    const u16* __restrict__ Bm, int ldb, int Nreal, int K,
    int GM, int GN,
    const float* __restrict__ bias, const float* __restrict__ bias2,
    const int* __restrict__ nrowsPtr, const int* __restrict__ rowmap,
    float* __restrict__ outF, u16* __restrict__ outH, float* __restrict__ outC)
{
    __shared__ u16 As[128][40];
    __shared__ u16 Bs[128][40];
    const int tid = threadIdx.x;
    const int GROUP = 8;
    int pid = blockIdx.x;
    int bpg = GROUP * GN;
    int group = pid / bpg;
    int first = group * GROUP;
    int gsz = min(GM - first, GROUP);
    int rem = pid - group * bpg;
    int bm = first + rem % gsz;
    int bn = rem / gsz;

    int MR = 0;
    if (MODE == 2) {
        MR = nrowsPtr[0];
        if (bm * 128 >= MR) return;   // compacted tail: nothing to do
    }

    const int w = tid >> 6, l = tid & 63;
    const int wr = (w >> 1) * 64, wc = (w & 1) * 64;
    const int lr = l & 15, lg = l >> 4;

    f32x4 acc[4][4] = {};

    for (int k0 = 0; k0 < K; k0 += 32) {
        __syncthreads();
        #pragma unroll
        for (int i = 0; i < 2; i++) {
            int L = tid * 8 + i * 2048;
            int r = L >> 5, c = L & 31;
            short8 v = {};
            int gr = bm * 128 + r;
            if (MODE != 2 || gr < MR) v = *(const short8*)&A[(size_t)gr * lda + k0 + c];
            *(short8*)&As[r][c] = v;
        }
        #pragma unroll
        for (int i = 0; i < 2; i++) {
            int L = tid * 8 + i * 2048;
            int r = L >> 5, c = L & 31;
            int gn = bn * 128 + r;
            short8 v = {};
            if (gn < Nreal) v = *(const short8*)&Bm[(size_t)gn * ldb + k0 + c];
            *(short8*)&Bs[r][c] = v;
        }
        __syncthreads();
        short8 af[4], bfr[4];
        #pragma unroll
        for (int m = 0; m < 4; m++) af[m] = *(const short8*)&As[wr + m * 16 + lr][lg * 8];
        #pragma unroll
        for (int n = 0; n < 4; n++) bfr[n] = *(const short8*)&Bs[wc + n * 16 + lr][lg * 8];
        #pragma unroll
        for (int m = 0; m < 4; m++)
            #pragma unroll
            for (int n = 0; n < 4; n++)
                acc[m][n] = __builtin_amdgcn_mfma_f32_16x16x32_bf16(af[m], bfr[n], acc[m][n], 0, 0, 0);
    }

    #pragma unroll
    for (int m = 0; m < 4; m++) {
        #pragma unroll
        for (int n = 0; n < 4; n++) {
            #pragma unroll
            for (int i = 0; i < 4; i++) {
                int row = bm * 128 + wr + m * 16 + lg * 4 + i;
                int col = bn * 128 + wc + n * 16 + lr;
                float v = acc[m][n][i];
                if (MODE == 0) {
                    outF[(size_t)row * 2048 + col] = v + bias[col];
                } else if (MODE == 1) {
                    if (col < 512) outH[row * 512 + col] = f2bf(v + bias[col]);
                    else outC[row * 512 + (col - 512)] = v + bias2[col - 512];
                } else {
                    if (row < MR && col < Nreal) {
                        int map = rowmap[row];
                        int b = map & 127, t = map >> 7;
                        outF[(size_t)b * ((size_t)TM * NV) + (size_t)t * NV + col] = v + bias[col];
                    }
                }
            }
        }
    }
}

// ---------------- persistent LSTM: all 49 steps in one kernel ----------------
// 64 WGs = 4 row-groups x 16 col-blocks. h exchange via agent-scope relaxed atomics.
// Barrier is GROUP-LOCAL (16 WGs sharing the row-block); X[t] prefetched before the
// poll so its HBM latency hides under the wait.
__global__ __launch_bounds__(256, 1) void lstm_all(
    const u16* __restrict__ Whh, const float* __restrict__ X,
    u16* __restrict__ hb0, u16* __restrict__ hb1,
    const float* __restrict__ cf, u16* __restrict__ HnewC,
    const int* __restrict__ decl, unsigned* __restrict__ slots,
    const int* __restrict__ offs)
{
    __shared__ u16 As[32][520];       // h rows, full K=512, padded
    __shared__ float gs[4][32][40];   // gate exchange
    const int tid = threadIdx.x;
    const int wg = blockIdx.x;
    const int rb = wg >> 4, cb = wg & 15;
    const int g = tid >> 6, l = tid & 63;
    const int lr = l & 15, lg = l >> 4;
    unsigned* gslots = slots + rb * 64;   // this group's 16 slots (256B apart per group)

    // epilogue coords (fixed across steps)
    const int erow = tid >> 3;            // 0..31
    const int ec4  = (tid & 7) * 4;       // 0..28
    const int egr  = rb * 32 + erow;      // batch row (sorted)
    const int egc  = cb * 32 + ec4;       // hidden col
    const int edec = decl[egr];

    // c state in registers (exclusive ownership)
    f32x4 creg = *(const f32x4*)&cf[(size_t)egr * 512 + egc];

    // Whh -> registers, once
    short8 bq[2][16];
    #pragma unroll
    for (int n = 0; n < 2; n++) {
        const u16* base = &Whh[(size_t)(g * 512 + cb * 32 + n * 16 + lr) * 512 + lg * 8];
        #pragma unroll
        for (int kk = 0; kk < 16; kk++)
            bq[n][kk] = *(const short8*)&base[kk * 32];
    }

    for (int t = 0; t < TM; t++) {
        const u16* hin = (t & 1) ? hb1 : hb0;
        u16* hout = (t & 1) ? hb0 : hb1;

        // prefetch X[t] + off[t] (independent of h) so latency hides under the poll
        const float* Xt = X + (size_t)t * 262144;
        size_t xb = (size_t)egr * 2048 + egc;
        f32x4 xi = *(const f32x4*)&Xt[xb];
        f32x4 xf = *(const f32x4*)&Xt[xb + 512];
        f32x4 xg = *(const f32x4*)&Xt[xb + 1024];
        f32x4 xo = *(const f32x4*)&Xt[xb + 1536];
        int offt = offs[t];

        // group-local barrier: wait until all 16 WGs of this row-group posted step t
        if (t > 0) {
            if (tid < 16) {
                while (__hip_atomic_load(&gslots[tid], __ATOMIC_RELAXED,
                                         __HIP_MEMORY_SCOPE_AGENT) < (unsigned)t)
                    __builtin_amdgcn_s_sleep(1);
            }
            __syncthreads();
        }

        // stage 32 rows x 512 cols of h into LDS via coherence-point atomic loads
        #pragma unroll
        for (int i = 0; i < 16; i++) {
            int L = i * 256 + tid;          // u64 index; 4096 total
            int r = L >> 7, cc = (L & 127) * 4;
            U64c u;
            u.u = __hip_atomic_load((const u64*)&hin[(size_t)(rb * 32 + r) * 512 + cc],
                                    __ATOMIC_RELAXED, __HIP_MEMORY_SCOPE_AGENT);
            *(us4*)&As[r][cc] = u.v;
        }
        __syncthreads();

        f32x4 acc[2][2] = {};
        #pragma unroll
        for (int kk = 0; kk < 16; kk++) {
            short8 af0 = *(const short8*)&As[lr][kk * 32 + lg * 8];
            short8 af1 = *(const short8*)&As[16 + lr][kk * 32 + lg * 8];
            acc[0][0] = __builtin_amdgcn_mfma_f32_16x16x32_bf16(af0, bq[0][kk], acc[0][0], 0, 0, 0);
            acc[0][1] = __builtin_amdgcn_mfma_f32_16x16x32_bf16(af0, bq[1][kk], acc[0][1], 0, 0, 0);
            acc[1][0] = __builtin_amdgcn_mfma_f32_16x16x32_bf16(af1, bq[0][kk], acc[1][0], 0, 0, 0);
            acc[1][1] = __builtin_amdgcn_mfma_f32_16x16x32_bf16(af1, bq[1][kk], acc[1][1], 0, 0, 0);
        }

        #pragma unroll
        for (int m = 0; m < 2; m++)
            #pragma unroll
            for (int n = 0; n < 2; n++)
                #pragma unroll
                for (int i = 0; i < 4; i++)
                    gs[g][m * 16 + lg * 4 + i][n * 16 + lr] = acc[m][n][i];
        __syncthreads();

        {
            f32x4 gi = *(const f32x4*)&gs[0][erow][ec4];
            f32x4 gf = *(const f32x4*)&gs[1][erow][ec4];
            f32x4 gg = *(const f32x4*)&gs[2][erow][ec4];
            f32x4 go = *(const f32x4*)&gs[3][erow][ec4];
            int act = (t < edec);
            us4 hv, hn;
            #pragma unroll
            for (int j = 0; j < 4; j++) {
                float iv = sigm(gi[j] + xi[j]);
                float fv = sigm(gf[j] + xf[j]);
                float gv = tanhf(gg[j] + xg[j]);
                float ov = sigm(go[j] + xo[j]);
                float cn = fv * creg[j] + iv * gv;
                float hn_f = ov * tanhf(cn);
                creg[j] = act ? cn : creg[j];
                float hold = bf2f(As[erow][egc + j]);
                float ho = act ? hn_f : hold;
                hv[j] = f2bf(ho);
                hn[j] = f2bf(hn_f);
            }
            U64c hu; hu.v = hv;
            __hip_atomic_store((u64*)&hout[(size_t)egr * 512 + egc], hu.u,
                               __ATOMIC_RELAXED, __HIP_MEMORY_SCOPE_AGENT);
            if (act)   // compacted Hnew: valid rows at step t are prefix 0..n_t
                *(us4*)&HnewC[(size_t)(offt + egr) * 512 + egc] = hn;
        }

        // drain stores (syncthreads implies vmcnt(0)), then post our slot
        __syncthreads();
        if (t < TM - 1 && tid == 0)
            __hip_atomic_store(&slots[rb * 64 + cb], (unsigned)(t + 1),
                               __ATOMIC_RELAXED, __HIP_MEMORY_SCOPE_AGENT);
    }
}

extern "C" void kernel_launch(void* const* d_in, const int* in_sizes, int n_in,
                              void* d_out, int out_size, void* d_ws, size_t ws_size,
                              hipStream_t stream) {
    const float* enc      = (const float*)d_in[0];
    const int*   captions = (const int*)d_in[1];
    const int*   caplens  = (const int*)d_in[2];
    const float* embW     = (const float*)d_in[3];
    const float* Wih      = (const float*)d_in[4];
    const float* Whh      = (const float*)d_in[5];
    const float* bih      = (const float*)d_in[6];
    const float* bhh      = (const float*)d_in[7];
    const float* fcW      = (const float*)d_in[8];
    const float* fcb      = (const float*)d_in[9];
    const float* ihW      = (const float*)d_in[10];
    const float* ihb      = (const float*)d_in[11];
    const float* icW      = (const float*)d_in[12];
    const float* icb      = (const float*)d_in[13];
    float* out = (float*)d_out;

    char* ws = (char*)d_ws;
    u16*   WihB = (u16*)(ws + 0);
    u16*   WhhB = (u16*)(ws + 2097152);
    u16*   fcWB = (u16*)(ws + 4194304);
    u16*   WhcB = (u16*)(ws + 14434304);
    u16*   encB = (u16*)(ws + 18628608);
    u16*   Xemb = (u16*)(ws + 19152896);
    float* X    = (float*)(ws + 25575424);
    u16*   HnewC= (u16*)(ws + 76955648);
    u16*   hb0  = (u16*)(ws + 83378176);
    u16*   hb1  = (u16*)(ws + 83509248);
    float* cf   = (float*)(ws + 83640320);
    int*   sidx = (int*)(ws + 83902464);
    int*   decl = (int*)(ws + 83902976);
    int*   capsS= (int*)(ws + 83903488);
    float* bsum = (float*)(ws + 83929088);
    unsigned* slots = (unsigned*)(ws + 83937280);   // 256 ints (4 groups x 64)
    int*   offs  = (int*)(ws + 83938304);           // 50 ints; offs[49] = nrowsC
    int*   rowmap= (int*)(ws + 83938560);           // 6272 ints

    k_sort<<<1, 128, 0, stream>>>(caplens, captions, bih, bhh, sidx, decl, capsS, bsum,
                                  out + 62720000, slots, offs, rowmap);
    k_zero<<<6272, 256, 0, stream>>>(decl, out);
    k_cvt<<<9096, 256, 0, stream>>>(Wih, Whh, fcW, ihW, icW, WihB, WhhB, fcWB, WhcB);
    k_gather<<<3392, 256, 0, stream>>>(enc, embW, sidx, capsS, encB, Xemb);
    // h0 | c0 : (128 x 1024) = encB (128x2048) @ WhcB^T
    gemm128<1><<<8, 256, 0, stream>>>(encB, 2048, WhcB, 2048, 1024, 2048, 1, 8,
                                      ihb, icb, nullptr, nullptr, nullptr, hb0, cf);
    // X = Xemb (6272x512) @ WihB^T (2048x512) + (b_ih+b_hh)
    gemm128<0><<<784, 256, 0, stream>>>(Xemb, 512, WihB, 512, 2048, 512, 49, 16,
                                        bsum, nullptr, nullptr, nullptr, X, nullptr, nullptr);
    // all 49 LSTM steps in one persistent kernel (writes compacted Hnew)
    lstm_all<<<NWG, 256, 0, stream>>>(WhhB, X, hb0, hb1, cf, HnewC, decl, slots, offs);
    // predictions = HnewC (nrowsC x 512) @ fcWB^T (10000x512) + fc_b, rowmap scatter
    gemm128<2><<<3871, 256, 0, stream>>>(HnewC, 512, fcWB, 512, NV, 512, 49, 79,
                                         fcb, nullptr, offs + 49, rowmap, out, nullptr, nullptr);
}